// Round 2
// baseline (486.332 us; speedup 1.0000x reference)
//
#include <hip/hip_runtime.h>

typedef _Float16 f16;
typedef _Float16 half8 __attribute__((ext_vector_type(8)));
typedef _Float16 half4 __attribute__((ext_vector_type(4)));
typedef float f32x4 __attribute__((ext_vector_type(4)));

#define B_ 2
#define S_ 2048
#define DM_ 2048
#define H_ 16
#define HD_ 128
#define EQ_ 6144              // (H + 2*HKV) * HD = 48*128
#define SCALE_Q 0.08838834764831845f   // 1/sqrt(128)

// ---------------- cast fp32 -> fp16 (same layout) ----------------
__global__ void k_cast(const float* __restrict__ in, f16* __restrict__ out, int n4) {
  int i = blockIdx.x * blockDim.x + threadIdx.x;
  int stride = gridDim.x * blockDim.x;
  for (; i < n4; i += stride) {
    float4 v = ((const float4*)in)[i];
    half4 h = { (f16)v.x, (f16)v.y, (f16)v.z, (f16)v.w };
    ((half4*)out)[i] = h;
  }
}

// ------------- transpose+cast: in[K][N] fp32 -> out[N][K] fp16 -------------
__global__ void k_tcast(const float* __restrict__ in, f16* __restrict__ out, int K, int N) {
  __shared__ float tile[64][65];
  const int t = threadIdx.x;
  const int nb = blockIdx.x * 64, kb = blockIdx.y * 64;
  const int tr = t >> 4, tc4 = (t & 15) * 4;
  #pragma unroll
  for (int i = 0; i < 4; ++i) {
    int k = tr + i * 16;
    float4 v = *(const float4*)&in[(size_t)(kb + k) * N + nb + tc4];
    tile[k][tc4 + 0] = v.x; tile[k][tc4 + 1] = v.y;
    tile[k][tc4 + 2] = v.z; tile[k][tc4 + 3] = v.w;
  }
  __syncthreads();
  #pragma unroll
  for (int i = 0; i < 4; ++i) {
    int n = tr + i * 16;
    half4 h = { (f16)tile[tc4 + 0][n], (f16)tile[tc4 + 1][n],
                (f16)tile[tc4 + 2][n], (f16)tile[tc4 + 3][n] };
    *(half4*)&out[(size_t)(nb + n) * K + kb + tc4] = h;
  }
}

// ---------------- fp16 MFMA GEMM: C[M][N] = A[M][K] * Bt[N][K]^T ----------------
// 128x128 tile, BK=64, 4 waves (2x2 of 64x64), reg-staged LDS with XOR swizzle.
__global__ __launch_bounds__(256, 2) void k_gemm(
    const f16* __restrict__ A, const f16* __restrict__ Bt,
    f16* __restrict__ C16, float* __restrict__ C32,
    int M, int N, int K, int writeF32)
{
  __shared__ __attribute__((aligned(16))) f16 As[128 * 64];
  __shared__ __attribute__((aligned(16))) f16 Bs[128 * 64];
  const int t = threadIdx.x;
  const int lane = t & 63, wave = t >> 6;
  const int lr = lane & 15, hi4 = lane >> 4;
  const int wr = wave >> 1, wc = wave & 1;
  const int row0 = blockIdx.x * 128, col0 = blockIdx.y * 128;

  const int sr = t >> 1;          // staging row 0..127
  const int sc0 = (t & 1) * 4;    // chunk base (8-half chunks)
  const f16* ga = &A[(size_t)(row0 + sr) * K + sc0 * 8];
  const f16* gb = &Bt[(size_t)(col0 + sr) * K + sc0 * 8];

  half8 ra[4], rb[4];
  #pragma unroll
  for (int i = 0; i < 4; ++i) {
    ra[i] = *(const half8*)(ga + i * 8);
    rb[i] = *(const half8*)(gb + i * 8);
  }

  f32x4 acc[4][4];
  #pragma unroll
  for (int m = 0; m < 4; ++m)
    #pragma unroll
    for (int n = 0; n < 4; ++n)
      acc[m][n] = (f32x4){0.f, 0.f, 0.f, 0.f};

  char* asb = (char*)As;
  char* bsb = (char*)Bs;
  const int nk = K >> 6;
  for (int kt = 0; kt < nk; ++kt) {
    __syncthreads();
    #pragma unroll
    for (int i = 0; i < 4; ++i) {
      int cc = (sc0 + i) ^ (sr & 7);
      *(half8*)(asb + sr * 128 + cc * 16) = ra[i];
      *(half8*)(bsb + sr * 128 + cc * 16) = rb[i];
    }
    __syncthreads();
    if (kt + 1 < nk) {
      #pragma unroll
      for (int i = 0; i < 4; ++i) {
        ra[i] = *(const half8*)(ga + (kt + 1) * 64 + i * 8);
        rb[i] = *(const half8*)(gb + (kt + 1) * 64 + i * 8);
      }
    }
    #pragma unroll
    for (int ks = 0; ks < 2; ++ks) {
      half8 af[4], bf[4];
      #pragma unroll
      for (int m = 0; m < 4; ++m) {
        int ar = wr * 64 + m * 16 + lr;
        af[m] = *(const half8*)(asb + ar * 128 + (((ks * 4 + hi4) ^ (ar & 7)) << 4));
      }
      #pragma unroll
      for (int n = 0; n < 4; ++n) {
        int br = wc * 64 + n * 16 + lr;
        bf[n] = *(const half8*)(bsb + br * 128 + (((ks * 4 + hi4) ^ (br & 7)) << 4));
      }
      #pragma unroll
      for (int m = 0; m < 4; ++m)
        #pragma unroll
        for (int n = 0; n < 4; ++n)
          acc[m][n] = __builtin_amdgcn_mfma_f32_16x16x32_f16(af[m], bf[n], acc[m][n], 0, 0, 0);
    }
  }
  #pragma unroll
  for (int m = 0; m < 4; ++m)
    #pragma unroll
    for (int n = 0; n < 4; ++n)
      #pragma unroll
      for (int j = 0; j < 4; ++j) {
        int row = row0 + wr * 64 + m * 16 + hi4 * 4 + j;
        int col = col0 + wc * 64 + n * 16 + lr;
        if (writeF32) C32[(size_t)row * N + col] = acc[m][n][j];
        else          C16[(size_t)row * N + col] = (f16)acc[m][n][j];
      }
}

// ---------------- RoPE on q,k heads; writes Q (scaled) and K planes ----------------
__global__ void k_rope(const f16* __restrict__ qkv, const float* __restrict__ cosb,
                       const float* __restrict__ sinb, f16* __restrict__ Qf, f16* __restrict__ Kf)
{
  const int bx = blockIdx.x;              // B*S*16
  const int bs = bx >> 4;
  const int h = (bx & 15) * 2 + (threadIdx.x >> 7);   // 0..31 (q:0-15, k:16-31)
  const int d = threadIdx.x & 127;
  const int s = bs & (S_ - 1);
  const int b = bs >> 11;
  float x  = (float)qkv[(size_t)bs * EQ_ + h * HD_ + d];
  float xp = (float)qkv[(size_t)bs * EQ_ + h * HD_ + (d ^ 64)];
  float sgn = (d < 64) ? -1.0f : 1.0f;
  float v = x * cosb[s * HD_ + d] + sgn * xp * sinb[s * HD_ + d];
  if (h < H_) {
    v *= SCALE_Q;
    Qf[(((size_t)(b * H_ + h)) * S_ + s) * HD_ + d] = (f16)v;
  } else {
    Kf[(((size_t)(b * H_ + (h - H_))) * S_ + s) * HD_ + d] = (f16)v;
  }
}

// ---------------- V transpose: qkv v-heads -> VT[B][H][D][S] fp16 ----------------
__global__ void k_vtrans(const f16* __restrict__ qkv, f16* __restrict__ VT)
{
  __shared__ __attribute__((aligned(16))) f16 tile[128][136];
  const int bx = blockIdx.x;              // B*H*(S/128) = 512
  const int st = bx & 15, h = (bx >> 4) & 15, b = bx >> 8;
  const int t = threadIdx.x;
  const int sl = t >> 1, dc = (t & 1) * 64;
  const int bs = b * S_ + st * 128 + sl;
  #pragma unroll
  for (int i = 0; i < 8; ++i) {
    half8 v = *(const half8*)&qkv[(size_t)bs * EQ_ + (32 + h) * HD_ + dc + i * 8];
    *(half8*)&tile[sl][dc + i * 8] = v;
  }
  __syncthreads();
  const int dr = t >> 1, scc = (t & 1) * 64;
  #pragma unroll
  for (int i = 0; i < 8; ++i) {
    half8 v;
    #pragma unroll
    for (int j = 0; j < 8; ++j) v[j] = tile[scc + i * 8 + j][dr];
    *(half8*)&VT[(((size_t)(b * H_ + h)) * HD_ + dr) * S_ + st * 128 + scc + i * 8] = v;
  }
}

// ---------------- flash attention: 4 waves x 32 q-rows, KT=64 ----------------
__global__ __launch_bounds__(256, 2) void k_attn(
    const f16* __restrict__ Qf, const f16* __restrict__ Kf, const f16* __restrict__ VT,
    f16* __restrict__ Oout)
{
  __shared__ __attribute__((aligned(16))) char lds[64 * 272 + 128 * 160 + 4 * 32 * 160];
  char* Ks = lds;                      // [64 tok][128 d + pad]  (272B rows)
  char* Vs = lds + 64 * 272;           // [128 d][64 tok + pad]  (160B rows)
  char* Ps = Vs + 128 * 160;           // per-wave [32 q][64 tok + pad] (160B rows)
  const int bx = blockIdx.x;           // B*H*(S/128) = 512
  const int qt = bx & 15, h = (bx >> 4) & 15, b = bx >> 8;
  const int t = threadIdx.x, lane = t & 63, wave = t >> 6;
  const int lr = lane & 15, hi4 = lane >> 4;
  const size_t bh = (size_t)(b * H_ + h);
  const int q0 = qt * 128 + wave * 32;

  half8 qf[2][4];
  #pragma unroll
  for (int m = 0; m < 2; ++m)
    #pragma unroll
    for (int ds = 0; ds < 4; ++ds)
      qf[m][ds] = *(const half8*)&Qf[(bh * S_ + q0 + m * 16 + lr) * HD_ + ds * 32 + hi4 * 8];

  f32x4 o[2][8];
  #pragma unroll
  for (int m = 0; m < 2; ++m)
    #pragma unroll
    for (int dc = 0; dc < 8; ++dc) o[m][dc] = (f32x4){0.f, 0.f, 0.f, 0.f};
  float mstate[2][4], lstate[2][4];
  #pragma unroll
  for (int m = 0; m < 2; ++m)
    #pragma unroll
    for (int j = 0; j < 4; ++j) { mstate[m][j] = -1e30f; lstate[m][j] = 0.f; }

  const int kr = t >> 2;               // K staging row 0..63 (4 threads/row)
  const int vr = t >> 1;               // V staging row 0..127 (2 threads/row)
  const f16* Kg = &Kf[bh * S_ * HD_];
  const f16* Vg = &VT[bh * HD_ * S_];

  for (int kt = 0; kt < S_ / 64; ++kt) {
    __syncthreads();
    // K rows are 256B (16 chunks of 16B): 4 threads x 4 chunks
    #pragma unroll
    for (int i = 0; i < 4; ++i) {
      int c = (t & 3) + i * 4;
      *(half8*)(Ks + kr * 272 + c * 16) = *(const half8*)&Kg[(size_t)(kt * 64 + kr) * HD_ + c * 8];
    }
    // V rows are 128B (8 chunks of 16B): 2 threads x 4 chunks
    #pragma unroll
    for (int i = 0; i < 4; ++i) {
      int c = (t & 1) + i * 2;
      *(half8*)(Vs + vr * 160 + c * 16) = *(const half8*)&Vg[(size_t)vr * S_ + kt * 64 + c * 8];
    }
    __syncthreads();

    f32x4 sc[2][4];
    #pragma unroll
    for (int m = 0; m < 2; ++m)
      #pragma unroll
      for (int n = 0; n < 4; ++n) sc[m][n] = (f32x4){0.f, 0.f, 0.f, 0.f};
    #pragma unroll
    for (int ds = 0; ds < 4; ++ds) {
      half8 kf[4];
      #pragma unroll
      for (int n = 0; n < 4; ++n)
        kf[n] = *(const half8*)(Ks + (n * 16 + lr) * 272 + ds * 64 + hi4 * 16);
      #pragma unroll
      for (int m = 0; m < 2; ++m)
        #pragma unroll
        for (int n = 0; n < 4; ++n)
          sc[m][n] = __builtin_amdgcn_mfma_f32_16x16x32_f16(qf[m][ds], kf[n], sc[m][n], 0, 0, 0);
    }

    // ---- online softmax (row stats per (m,j), reduce over lanes&15) ----
    float mx[2][4], corr[2][4], rs[2][4];
    #pragma unroll
    for (int m = 0; m < 2; ++m)
      #pragma unroll
      for (int j = 0; j < 4; ++j)
        mx[m][j] = fmaxf(fmaxf(sc[m][0][j], sc[m][1][j]), fmaxf(sc[m][2][j], sc[m][3][j]));
    #pragma unroll
    for (int mask = 1; mask < 16; mask <<= 1)
      #pragma unroll
      for (int m = 0; m < 2; ++m)
        #pragma unroll
        for (int j = 0; j < 4; ++j)
          mx[m][j] = fmaxf(mx[m][j], __shfl_xor(mx[m][j], mask));
    #pragma unroll
    for (int m = 0; m < 2; ++m)
      #pragma unroll
      for (int j = 0; j < 4; ++j) {
        float nm = fmaxf(mstate[m][j], mx[m][j]);
        corr[m][j] = __expf(mstate[m][j] - nm);
        mstate[m][j] = nm;
        rs[m][j] = 0.f;
      }
    #pragma unroll
    for (int m = 0; m < 2; ++m)
      #pragma unroll
      for (int n = 0; n < 4; ++n)
        #pragma unroll
        for (int j = 0; j < 4; ++j) {
          float p = __expf(sc[m][n][j] - mstate[m][j]);
          sc[m][n][j] = p;
          rs[m][j] += p;
        }
    #pragma unroll
    for (int mask = 1; mask < 16; mask <<= 1)
      #pragma unroll
      for (int m = 0; m < 2; ++m)
        #pragma unroll
        for (int j = 0; j < 4; ++j)
          rs[m][j] += __shfl_xor(rs[m][j], mask);
    #pragma unroll
    for (int m = 0; m < 2; ++m)
      #pragma unroll
      for (int j = 0; j < 4; ++j)
        lstate[m][j] = lstate[m][j] * corr[m][j] + rs[m][j];
    #pragma unroll
    for (int m = 0; m < 2; ++m)
      #pragma unroll
      for (int dc = 0; dc < 8; ++dc)
        #pragma unroll
        for (int j = 0; j < 4; ++j) o[m][dc][j] *= corr[m][j];

    // ---- P -> LDS (fp16), re-fragment for PV ----
    #pragma unroll
    for (int m = 0; m < 2; ++m)
      #pragma unroll
      for (int n = 0; n < 4; ++n)
        #pragma unroll
        for (int j = 0; j < 4; ++j) {
          int prow = wave * 32 + m * 16 + hi4 * 4 + j;
          *(f16*)(Ps + prow * 160 + (n * 16 + lr) * 2) = (f16)sc[m][n][j];
        }
    __syncthreads();   // ordering P writes vs P reads (conservative, avoids TBAA risk)

    #pragma unroll
    for (int ks = 0; ks < 2; ++ks) {
      half8 pa[2];
      #pragma unroll
      for (int m = 0; m < 2; ++m)
        pa[m] = *(const half8*)(Ps + (wave * 32 + m * 16 + lr) * 160 + ks * 64 + hi4 * 16);
      #pragma unroll
      for (int dc = 0; dc < 8; ++dc) {
        half8 vb = *(const half8*)(Vs + (dc * 16 + lr) * 160 + ks * 64 + hi4 * 16);
        #pragma unroll
        for (int m = 0; m < 2; ++m)
          o[m][dc] = __builtin_amdgcn_mfma_f32_16x16x32_f16(pa[m], vb, o[m][dc], 0, 0, 0);
      }
    }
  }

  float inv[2][4];
  #pragma unroll
  for (int m = 0; m < 2; ++m)
    #pragma unroll
    for (int j = 0; j < 4; ++j) inv[m][j] = 1.0f / lstate[m][j];
  #pragma unroll
  for (int m = 0; m < 2; ++m)
    #pragma unroll
    for (int dc = 0; dc < 8; ++dc)
      #pragma unroll
      for (int j = 0; j < 4; ++j) {
        int row = b * S_ + qt * 128 + wave * 32 + m * 16 + hi4 * 4 + j;
        int col = h * 128 + dc * 16 + lr;
        Oout[(size_t)row * DM_ + col] = (f16)(o[m][dc][j] * inv[m][j]);
      }
}

extern "C" void kernel_launch(void* const* d_in, const int* in_sizes, int n_in,
                              void* d_out, int out_size, void* d_ws, size_t ws_size,
                              hipStream_t stream) {
  (void)in_sizes; (void)n_in; (void)out_size; (void)ws_size;
  const float* hidden = (const float*)d_in[0];
  const float* cosb   = (const float*)d_in[1];
  const float* sinb   = (const float*)d_in[2];
  const float* W_qkv  = (const float*)d_in[3];
  const float* W_o    = (const float*)d_in[4];
  float* out = (float*)d_out;

  f16* Ah    = (f16*)d_ws;                 // [4096][2048]
  f16* Wqt   = Ah    + (size_t)8388608;    // [6144][2048]
  f16* Wot   = Wqt   + (size_t)12582912;   // [2048][2048]
  f16* qkv16 = Wot   + (size_t)4194304;    // [4096][6144]
  f16* Qf    = qkv16 + (size_t)25165824;   // [2][16][2048][128]
  f16* Kf    = Qf    + (size_t)8388608;
  f16* VT    = Kf    + (size_t)8388608;    // [2][16][128][2048]
  f16* AO    = VT    + (size_t)8388608;    // [4096][2048]

  k_cast<<<2048, 256, 0, stream>>>(hidden, Ah, 2097152);
  k_tcast<<<dim3(EQ_ / 64, 2048 / 64), 256, 0, stream>>>(W_qkv, Wqt, 2048, EQ_);
  k_tcast<<<dim3(2048 / 64, 2048 / 64), 256, 0, stream>>>(W_o, Wot, 2048, 2048);
  k_gemm<<<dim3(32, EQ_ / 128), 256, 0, stream>>>(Ah, Wqt, qkv16, nullptr, 4096, EQ_, 2048, 0);
  k_rope<<<B_ * S_ * 16, 256, 0, stream>>>(qkv16, cosb, sinb, Qf, Kf);
  k_vtrans<<<512, 256, 0, stream>>>(qkv16, VT);
  k_attn<<<512, 256, 0, stream>>>(Qf, Kf, VT, AO);
  k_gemm<<<dim3(32, 16), 256, 0, stream>>>(AO, Wot, nullptr, out, 4096, 2048, 2048, 1);
}